// Round 1
// baseline (107.908 us; speedup 1.0000x reference)
//
#include <hip/hip_runtime.h>

// RoIAlign (max-pool variant) for MI355X — fp32, R7.
//  K1: LDS-tiled transpose (B,C,HW) -> (B,HW,C)  (unchanged).
//  K2 NEW (vs R6): block = (roi, 128-channel half); lane = 2 channels
//      (float2). LDS drops 54.9KB -> 29.2KB => 5 blocks/CU (was 2) =
//      5 waves/SIMD for gather-latency hiding. Stage LD=129 (odd) =>
//      phase-3 LDS reads bank-conflict-free (was 8-way at LD=260);
//      phase-2 stores are 2 scalar ds_write (alignment-free). Waves now
//      take CONTIGUOUS bin ranges (12/12/12/13) so consecutive bins'
//      3x3 patches overlap (share 2 of 3 columns + all rows) -> L1 reuse.
//      Grid 1024 -> 2048 blocks; per-block output is a contiguous
//      6272-float region (no cross-block cache-line sharing).
// Numerics identical to R2-R6 (same per-component op order) — absmax 0.0156.

namespace {

constexpr int B_ = 4, C_ = 256, H_ = 50, W_ = 50;
constexpr int HW = H_ * W_;                     // 2500
constexpr int HO = 7, WO = 7, NBIN = HO * WO;   // 49
constexpr int CH = 128;                          // channels per block
constexpr int OUT_PER_ROI = C_ * NBIN;          // 12544
constexpr int OUT_HALF = CH * NBIN;             // 6272
constexpr int LD = 129;                          // odd => conflict-free reads
constexpr float RATIO = 1.0f / 32.0f;

// ---------------- K1: tiled transpose (B,C,HW) -> (B,HW,C) ----------------
__global__ __launch_bounds__(256) void transpose_tiled(
    const float* __restrict__ f, float* __restrict__ ft)
{
    __shared__ float tile[64][65];
    const int bt   = blockIdx.x;
    const int hw_t = bt % 40;
    const int c_t  = (bt / 40) % 4;
    const int b    = bt / 160;
    const int hw0 = hw_t * 64, c0 = c_t * 64;
    const int lx = threadIdx.x & 63;
    const int ly = threadIdx.x >> 6;

#pragma unroll
    for (int k = 0; k < 16; ++k) {
        const int c  = c0 + k * 4 + ly;
        const int hw = hw0 + lx;
        if (hw < HW)
            tile[k * 4 + ly][lx] = f[((size_t)b * C_ + c) * HW + hw];
    }
    __syncthreads();
#pragma unroll
    for (int k = 0; k < 16; ++k) {
        const int hw = hw0 + k * 4 + ly;
        if (hw < HW)
            ft[((size_t)b * HW + hw) * C_ + c0 + lx] = tile[lx][k * 4 + ly];
    }
}

// Corner selection with compile-time patch indices (float2 = 2 channels).
// AX/AY = whether sample 1's floor is one past sample 0's.
// Weight packing: wa = (wxh0,wxh1,wxl0,wxl1), wb = (wyb0,wyb1,wyt0,wyt1).
template<int AX, int AY>
__device__ __forceinline__ float2 bin_max2(const float2 p[3][3],
                                           const float4 wa, const float4 wb)
{
    float2 s[2][2];
#pragma unroll
    for (int sy = 0; sy < 2; ++sy) {
#pragma unroll
        for (int sx = 0; sx < 2; ++sx) {
            const int xk = AX * sx, yj = AY * sy;
            const float wxh = sx ? wa.y : wa.x;
            const float wxl = sx ? wa.w : wa.z;
            const float wyb = sy ? wb.y : wb.x;
            const float wyt = sy ? wb.w : wb.z;
            const float2 tl = p[yj][xk],     tr = p[yj][xk + 1];
            const float2 bl = p[yj + 1][xk], br = p[yj + 1][xk + 1];
            float2 o;
            o.x = wyb * (wxh * br.x + wxl * bl.x) + wyt * (wxh * tr.x + wxl * tl.x);
            o.y = wyb * (wxh * br.y + wxl * bl.y) + wyt * (wxh * tr.y + wxl * tl.y);
            s[sy][sx] = o;
        }
    }
    float2 m;
    m.x = fmaxf(fmaxf(s[0][0].x, s[0][1].x), fmaxf(s[1][0].x, s[1][1].x));
    m.y = fmaxf(fmaxf(s[0][0].y, s[0][1].y), fmaxf(s[1][0].y, s[1][1].y));
    return m;
}

// ---------------- K2: main ----------------
__global__ __launch_bounds__(256, 5) void roialign_main(
    const float* __restrict__ ft,       // (B,HW,C)
    const float* __restrict__ rois,
    float* __restrict__ out)
{
    __shared__ float stage[NBIN * LD];                   // 25,284 B
    __shared__ __align__(16) float    wts[NBIN][8];      // wxh0,wxh1,wxl0,wxl1,wyb0,wyb1,wyt0,wyt1 (x valid)
    __shared__ __align__(16) unsigned offp[NBIN][12];    // [0..8]=3x3 patch hw offsets, [9]=ax|(ay<<1)

    const int bid  = blockIdx.x;
    const int n    = bid >> 1;          // roi
    const int half = bid & 1;           // channel half (0: ch 0-127, 1: 128-255)
    const int tid  = threadIdx.x;
    const int wave = tid >> 6;
    const int lane = tid & 63;
    const float fW = (float)W_, fH = (float)H_;

    // ---- Phase 1: per-bin geometry (threads 0..48) ----
    if (tid < NBIN) {
        const int ii = tid / WO, jj = tid % WO;
        const float* r = rois + n * 5;
        const float bx1 = fminf(fmaxf(r[1] * RATIO, 0.0f), fW);
        const float by1 = fminf(fmaxf(r[2] * RATIO, 0.0f), fH);
        const float bx2 = fminf(fmaxf(r[3] * RATIO, 0.0f), fW);
        const float by2 = fminf(fmaxf(r[4] * RATIO, 0.0f), fH);
        const bool roi_valid = (bx2 - bx1 > 0.0f) && (by2 - by1 > 0.0f);
        const float bin_w = (bx2 - bx1) * (1.0f / (float)WO);
        const float bin_h = (by2 - by1) * (1.0f / (float)HO);

        const float x1u = bx1 + (float)jj * bin_w;
        const float x1b = fminf(fmaxf(x1u, 0.0f), fW);
        const float x2b = fminf(fmaxf(x1u + bin_w, 0.0f), fW);
        const float y1u = by1 + (float)ii * bin_h;
        const float y1b = fminf(fmaxf(y1u, 0.0f), fH);
        const float y2b = fminf(fmaxf(y1u + bin_h, 0.0f), fH);
        const float vf = (roi_valid && (y2b > y1b) && (x2b > x1b)) ? 1.0f : 0.0f;

        int xl[2], yl[2];
#pragma unroll
        for (int s = 0; s < 2; ++s) {
            const float px = x1b + ((float)s + 0.5f) * (bin_w * 0.5f);
            int l = (int)floorf(px);
            l = min(max(l, 0), W_ - 1);
            const int h = min(l + 1, W_ - 1);
            xl[s] = l;
            wts[tid][0 + s] = vf * (px - (float)l);      // wxh[s]
            wts[tid][2 + s] = vf * ((float)h - px);      // wxl[s]

            const float py = y1b + ((float)s + 0.5f) * (bin_h * 0.5f);
            int t = (int)floorf(py);
            t = min(max(t, 0), H_ - 1);
            const int u = min(t + 1, H_ - 1);
            yl[s] = t;
            wts[tid][4 + s] = py - (float)t;             // wyb[s]
            wts[tid][6 + s] = (float)u - py;             // wyt[s]
        }
        // 3x3 patch covering all corners: sample spacing < 1 => floor diff <= 1.
        const int X0 = xl[0], Y0 = yl[0];
        const int ax = min(xl[1] - X0, 1);               // 0 or 1
        const int ay = min(yl[1] - Y0, 1);
        const int pxs0 = X0, pxs1 = min(X0 + 1, W_ - 1), pxs2 = min(X0 + 2, W_ - 1);
        const int pys0 = Y0, pys1 = min(Y0 + 1, H_ - 1), pys2 = min(Y0 + 2, H_ - 1);
        const int px_[3] = {pxs0, pxs1, pxs2};
        const int py_[3] = {pys0, pys1, pys2};
#pragma unroll
        for (int j = 0; j < 3; ++j)
#pragma unroll
            for (int k = 0; k < 3; ++k)
                offp[tid][j * 3 + k] = (unsigned)(py_[j] * W_ + px_[k]);
        offp[tid][9]  = (unsigned)(ax | (ay << 1));
        offp[tid][10] = 0u;
        offp[tid][11] = 0u;
    }
    __syncthreads();

    // ---- Phase 2: lane = 2 channels (float2); waves take contiguous bins ----
    int b = (int)rois[n * 5];
    b = min(max(b, 0), B_ - 1);
    const float2* pb = (const float2*)(ft + (size_t)b * HW * C_ + half * CH) + lane;

    const int s0 = (wave * NBIN) >> 2;        // 0,12,24,36
    const int e0 = ((wave + 1) * NBIN) >> 2;  // 12,24,36,49
    for (int bin = s0; bin < e0; ++bin) {
        const float4 wa = *(const float4*)wts[bin];
        const float4 wb = *(const float4*)(wts[bin] + 4);
        const uint4 o0 = *(const uint4*)&offp[bin][0];   // p00 p01 p02 p10
        const uint4 o1 = *(const uint4*)&offp[bin][4];   // p11 p12 p20 p21
        const uint2 o2 = *(const uint2*)&offp[bin][8];   // p22, flags

        float2 p[3][3];
        p[0][0] = pb[(int)o0.x << 7];
        p[0][1] = pb[(int)o0.y << 7];
        p[0][2] = pb[(int)o0.z << 7];
        p[1][0] = pb[(int)o0.w << 7];
        p[1][1] = pb[(int)o1.x << 7];
        p[1][2] = pb[(int)o1.y << 7];
        p[2][0] = pb[(int)o1.z << 7];
        p[2][1] = pb[(int)o1.w << 7];
        p[2][2] = pb[(int)o2.x << 7];

        float2 m;
        switch (o2.y) {                      // wave-uniform: no divergence
            case 0u:  m = bin_max2<0, 0>(p, wa, wb); break;
            case 1u:  m = bin_max2<1, 0>(p, wa, wb); break;
            case 2u:  m = bin_max2<0, 1>(p, wa, wb); break;
            default:  m = bin_max2<1, 1>(p, wa, wb); break;
        }

        // LD is odd: scalar stores (2x ds_write_b32), ~4-way on stores only.
        stage[bin * LD + 2 * lane]     = m.x;
        stage[bin * LD + 2 * lane + 1] = m.y;
    }
    __syncthreads();

    // ---- Phase 3: coalesced write (transpose bin-major -> ch-major) ----
    // Read addr = bin*129 + ch; lane-consecutive bins => bank stride 1 (no conflict).
    float* outn = out + (size_t)n * OUT_PER_ROI + (size_t)half * OUT_HALF;
    for (int k = tid; k < OUT_HALF; k += 256) {
        const int ch  = k / NBIN;
        const int bin = k - ch * NBIN;
        outn[k] = stage[bin * LD + ch];
    }
}

} // namespace

extern "C" void kernel_launch(void* const* d_in, const int* in_sizes, int n_in,
                              void* d_out, int out_size, void* d_ws, size_t ws_size,
                              hipStream_t stream)
{
    const float* feats = (const float*)d_in[0];
    const float* rois  = (const float*)d_in[1];
    float* out = (float*)d_out;
    const int N = in_sizes[1] / 5;                    // 1024
    float* ft = (float*)d_ws;                         // 10.24 MB

    hipLaunchKernelGGL(transpose_tiled, dim3(B_ * 4 * 40), dim3(256), 0, stream,
                       feats, ft);
    hipLaunchKernelGGL(roialign_main, dim3(N * 2), dim3(256), 0, stream,
                       ft, rois, out);
}